// Round 1
// baseline (2432.453 us; speedup 1.0000x reference)
//
#include <hip/hip_runtime.h>
#include <math.h>

// Sizes (from reference setup): B=8, S=2048, F=1024, all fp32.
// out[b,s,:] = diag[b,s] * (value[b,s,:] @ Wv^T), where
// diag[b,j] = exp(s_jj - m_j) / sum_i exp(s_ij - m_j),
// s_ij = (1/sqrt(F)) * dot(q_t[b,i,:], k_t[b,j,:]).

#define TILE 64
#define BK   16
#define IC   4   // i-chunks in col_stats (occupancy)

// Y[m][n] = (rowscale ? rowscale[m] : 1) * sum_k X[m][k] * W[n][k]
// X: MxK row-major, W: NxK row-major (nn.Linear weight), Y: MxN.
__global__ __launch_bounds__(256)
void gemm_xwT_kernel(const float* __restrict__ X, const float* __restrict__ W,
                     float* __restrict__ Y, const float* __restrict__ rowscale,
                     int M, int N, int K) {
  // +4 pad keeps float4 alignment (stride 68*4=272B, 16B-aligned) and breaks
  // power-of-2 bank striding (2-way aliasing is free on CDNA4).
  __shared__ float As[BK][TILE + 4];
  __shared__ float Bs[BK][TILE + 4];
  const int bm = blockIdx.x * TILE;
  const int bn = blockIdx.y * TILE;
  const int tid = threadIdx.x;
  const int tr = (tid >> 4) << 2;   // 0..60 (i micro-tile)
  const int tc = (tid & 15) << 2;   // 0..60 (j micro-tile)
  const int lrow = tid >> 2;        // 0..63 (staging row)
  const int lk = (tid & 3) << 2;    // 0,4,8,12 (staging k)
  float acc[4][4] = {};
  const float* Xrow = X + (size_t)(bm + lrow) * K + lk;
  const float* Wrow = W + (size_t)(bn + lrow) * K + lk;
  for (int k0 = 0; k0 < K; k0 += BK) {
    const float4 a = *reinterpret_cast<const float4*>(Xrow + k0);
    const float4 b = *reinterpret_cast<const float4*>(Wrow + k0);
    As[lk + 0][lrow] = a.x; As[lk + 1][lrow] = a.y;
    As[lk + 2][lrow] = a.z; As[lk + 3][lrow] = a.w;
    Bs[lk + 0][lrow] = b.x; Bs[lk + 1][lrow] = b.y;
    Bs[lk + 2][lrow] = b.z; Bs[lk + 3][lrow] = b.w;
    __syncthreads();
#pragma unroll
    for (int kk = 0; kk < BK; ++kk) {
      const float4 av = *reinterpret_cast<const float4*>(&As[kk][tr]);
      const float4 bv = *reinterpret_cast<const float4*>(&Bs[kk][tc]);
      const float a0[4] = {av.x, av.y, av.z, av.w};
      const float b0[4] = {bv.x, bv.y, bv.z, bv.w};
#pragma unroll
      for (int i = 0; i < 4; ++i)
#pragma unroll
        for (int j = 0; j < 4; ++j)
          acc[i][j] = fmaf(a0[i], b0[j], acc[i][j]);
    }
    __syncthreads();
  }
#pragma unroll
  for (int i = 0; i < 4; ++i) {
    const float s = rowscale ? rowscale[bm + tr + i] : 1.0f;
    float4 o;
    o.x = acc[i][0] * s; o.y = acc[i][1] * s;
    o.z = acc[i][2] * s; o.w = acc[i][3] * s;
    *reinterpret_cast<float4*>(&Y[(size_t)(bm + tr + i) * N + bn + tc]) = o;
  }
}

// Per (batch b, j-tile of 64, i-chunk ic): online (max, sumexp) over the
// chunk's i range for each column j, plus diagonal score capture.
__global__ __launch_bounds__(256)
void col_stats_kernel(const float* __restrict__ qt, const float* __restrict__ kt,
                      float* __restrict__ mpart, float* __restrict__ lpart,
                      float* __restrict__ sdiag, int S, int F, float scale) {
  const int b = blockIdx.z;
  const int jb = blockIdx.x;
  const int ic = blockIdx.y;
  const int Bsz = gridDim.z;
  const float* q = qt + (size_t)b * S * F;
  const float* kx = kt + (size_t)b * S * F;
  const int j0 = jb * TILE;
  __shared__ float Qs[BK][TILE + 4];
  __shared__ float Ks[BK][TILE + 4];
  const int tid = threadIdx.x;
  const int tr = (tid >> 4) << 2;   // i micro-tile
  const int tc = (tid & 15) << 2;   // j micro-tile
  const int lrow = tid >> 2;
  const int lk = (tid & 3) << 2;
  float m[4], l[4];
#pragma unroll
  for (int j = 0; j < 4; ++j) { m[j] = -3.0e38f; l[j] = 0.0f; }
  const int chunk = S / IC;
  const int ibeg = ic * chunk;
  const int iend = ibeg + chunk;
  for (int i0 = ibeg; i0 < iend; i0 += TILE) {
    float acc[4][4] = {};  // [ii][jj] raw dot products
    const float* Qrow = q + (size_t)(i0 + lrow) * F + lk;
    const float* Krow = kx + (size_t)(j0 + lrow) * F + lk;
    for (int k0 = 0; k0 < F; k0 += BK) {
      const float4 a = *reinterpret_cast<const float4*>(Qrow + k0);
      const float4 c = *reinterpret_cast<const float4*>(Krow + k0);
      Qs[lk + 0][lrow] = a.x; Qs[lk + 1][lrow] = a.y;
      Qs[lk + 2][lrow] = a.z; Qs[lk + 3][lrow] = a.w;
      Ks[lk + 0][lrow] = c.x; Ks[lk + 1][lrow] = c.y;
      Ks[lk + 2][lrow] = c.z; Ks[lk + 3][lrow] = c.w;
      __syncthreads();
#pragma unroll
      for (int kk = 0; kk < BK; ++kk) {
        const float4 av = *reinterpret_cast<const float4*>(&Qs[kk][tr]);
        const float4 bv = *reinterpret_cast<const float4*>(&Ks[kk][tc]);
        const float a0[4] = {av.x, av.y, av.z, av.w};
        const float b0[4] = {bv.x, bv.y, bv.z, bv.w};
#pragma unroll
        for (int i = 0; i < 4; ++i)
#pragma unroll
          for (int j = 0; j < 4; ++j)
            acc[i][j] = fmaf(a0[i], b0[j], acc[i][j]);
      }
      __syncthreads();
    }
    // Diagonal capture: i-tile == j-tile, thread micro-tiles on the diagonal.
    if (i0 == j0 && tr == tc) {
#pragma unroll
      for (int jj = 0; jj < 4; ++jj)
        sdiag[(size_t)b * S + j0 + tc + jj] = acc[jj][jj] * scale;
    }
    // Online (m, l) update per column over this tile's 4 local i values.
#pragma unroll
    for (int jj = 0; jj < 4; ++jj) {
      const float t0 = acc[0][jj] * scale, t1 = acc[1][jj] * scale;
      const float t2 = acc[2][jj] * scale, t3 = acc[3][jj] * scale;
      const float tm = fmaxf(fmaxf(t0, t1), fmaxf(t2, t3));
      const float mn = fmaxf(m[jj], tm);
      l[jj] = l[jj] * __expf(m[jj] - mn) +
              __expf(t0 - mn) + __expf(t1 - mn) + __expf(t2 - mn) + __expf(t3 - mn);
      m[jj] = mn;
    }
  }
  // Cross-thread reduce: 16 partial (m,l) per column; reuse Qs/Ks as scratch.
  __syncthreads();
  const int pidx = tid >> 4;  // 0..15
#pragma unroll
  for (int jj = 0; jj < 4; ++jj) { Qs[pidx][tc + jj] = m[jj]; Ks[pidx][tc + jj] = l[jj]; }
  __syncthreads();
  if (tid < TILE) {
    float M = -3.0e38f;
#pragma unroll
    for (int p = 0; p < 16; ++p) M = fmaxf(M, Qs[p][tid]);
    float L = 0.0f;
#pragma unroll
    for (int p = 0; p < 16; ++p) L += Ks[p][tid] * __expf(Qs[p][tid] - M);
    const size_t idx = ((size_t)ic * Bsz + b) * S + j0 + tid;
    mpart[idx] = M;
    lpart[idx] = L;
  }
}

__global__ __launch_bounds__(256)
void combine_diag_kernel(const float* __restrict__ mpart, const float* __restrict__ lpart,
                         const float* __restrict__ sdiag, float* __restrict__ diag, int BS) {
  const int idx = blockIdx.x * 256 + threadIdx.x;
  if (idx >= BS) return;
  float M = -3.0e38f;
#pragma unroll
  for (int c = 0; c < IC; ++c) M = fmaxf(M, mpart[(size_t)c * BS + idx]);
  float L = 0.0f;
#pragma unroll
  for (int c = 0; c < IC; ++c)
    L += lpart[(size_t)c * BS + idx] * __expf(mpart[(size_t)c * BS + idx] - M);
  diag[idx] = __expf(sdiag[idx] - M) / L;
}

extern "C" void kernel_launch(void* const* d_in, const int* in_sizes, int n_in,
                              void* d_out, int out_size, void* d_ws, size_t ws_size,
                              hipStream_t stream) {
  const float* query = (const float*)d_in[0];
  const float* key   = (const float*)d_in[1];
  const float* value = (const float*)d_in[2];
  const float* Wq    = (const float*)d_in[3];
  const float* Wk    = (const float*)d_in[4];
  const float* Wv    = (const float*)d_in[5];

  const int F = 1024;                 // in_sizes[3] == F*F
  const int BS = in_sizes[0] / F;     // B*S = 16384
  const int B = 8;
  const int S = BS / B;               // 2048

  // Workspace layout (floats): qt[BS*F] kt[BS*F] mpart[IC*BS] lpart[IC*BS]
  // sdiag[BS] diag[BS]  -> ~128.7 MB
  float* ws    = (float*)d_ws;
  float* qt    = ws;
  float* kt    = qt + (size_t)BS * F;
  float* mpart = kt + (size_t)BS * F;
  float* lpart = mpart + (size_t)IC * BS;
  float* sdiag = lpart + (size_t)IC * BS;
  float* diag  = sdiag + BS;

  const dim3 blk(256);
  const dim3 ggrid(BS / TILE, F / TILE);  // 256 x 16

  hipLaunchKernelGGL(gemm_xwT_kernel, ggrid, blk, 0, stream,
                     query, Wq, qt, (const float*)nullptr, BS, F, F);
  hipLaunchKernelGGL(gemm_xwT_kernel, ggrid, blk, 0, stream,
                     key, Wk, kt, (const float*)nullptr, BS, F, F);

  const dim3 sgrid(S / TILE, IC, B);      // 32 x 4 x 8 = 1024 blocks
  hipLaunchKernelGGL(col_stats_kernel, sgrid, blk, 0, stream,
                     qt, kt, mpart, lpart, sdiag, S, F, 1.0f / sqrtf((float)F));

  hipLaunchKernelGGL(combine_diag_kernel, dim3((BS + 255) / 256), blk, 0, stream,
                     mpart, lpart, sdiag, diag, BS);

  hipLaunchKernelGGL(gemm_xwT_kernel, ggrid, blk, 0, stream,
                     value, Wv, (float*)d_out, diag, BS, F, F);
}

// Round 3
// 337.522 us; speedup vs baseline: 7.2068x; 7.2068x over previous
//
#include <hip/hip_runtime.h>
#include <math.h>

// B=8, S=2048, F=1024 fp32 in/out.
// out[b,s,:] = diag[b,s] * (value[b,s,:] @ Wv^T)
// diag[b,j] = exp(s_jj - M_j) / sum_i exp(s_ij - M_j),  s_ij = scale * <q_t_i, k_t_j>
// All dense stages in fp16 MFMA (16x16x32, fp32 accum), m97-style 128x128 tiles.

typedef _Float16 f16x8 __attribute__((ext_vector_type(8)));
typedef float    f32x4 __attribute__((ext_vector_type(4)));

#define COLIC 4          // i-chunks for col_stats grid (512 blocks)
#define SCALE 0.03125f   // 1/sqrt(1024), exact power of two

typedef __attribute__((address_space(1))) const unsigned int g_u32_t;
typedef __attribute__((address_space(3))) unsigned int l_u32_t;

__device__ __forceinline__ void gload16(const _Float16* g, _Float16* l) {
  // async global->LDS, 16 B per lane; LDS dest = wave-uniform base + lane*16
  __builtin_amdgcn_global_load_lds((g_u32_t*)g, (l_u32_t*)l, 16, 0, 0);
}

// Stage a 128x32 fp16 tile (global rows stride ldk) into LDS row-major [128][32].
__device__ __forceinline__ void stage_tile(const _Float16* gbase, int ldk,
                                           _Float16* lds, int w, int lane) {
#pragma unroll
  for (int c = 0; c < 2; ++c) {
    const int blk = c * 4 + w;                  // 0..7, wave-uniform
    const int r = (blk << 4) + (lane >> 2);     // row 0..127
    const _Float16* g = gbase + (size_t)r * ldk + ((lane & 3) << 3);
    gload16(g, lds + blk * 512);                // 512 fp16 = 1024 B per wave-call
  }
}

// fp32 -> fp16 elementwise (8 els/thread), optional multiply.
__global__ __launch_bounds__(256)
void conv_f32_f16(const float* __restrict__ src, _Float16* __restrict__ dst,
                  int n8, float mul) {
  for (int i = blockIdx.x * 256 + threadIdx.x; i < n8; i += gridDim.x * 256) {
    const float4 a = ((const float4*)src)[2 * i];
    const float4 b = ((const float4*)src)[2 * i + 1];
    f16x8 o;
    o[0] = (_Float16)(a.x * mul); o[1] = (_Float16)(a.y * mul);
    o[2] = (_Float16)(a.z * mul); o[3] = (_Float16)(a.w * mul);
    o[4] = (_Float16)(b.x * mul); o[5] = (_Float16)(b.y * mul);
    o[6] = (_Float16)(b.z * mul); o[7] = (_Float16)(b.w * mul);
    ((f16x8*)dst)[i] = o;
  }
}

// C[m][n] = sum_k A[m][k] * B[n][k];  A: MxK, B: NxK, both fp16 row-major.
// F16OUT=1: write fp16 C16.  F16OUT=0: write fp32 C32 scaled by rowscale[m].
template <int F16OUT>
__global__ __launch_bounds__(256)
void gemm_mfma(const _Float16* __restrict__ A, const _Float16* __restrict__ B,
               _Float16* __restrict__ C16, float* __restrict__ C32,
               const float* __restrict__ rowscale, int M, int N, int Kd) {
  __shared__ __align__(16) _Float16 As[128 * 32];
  __shared__ __align__(16) _Float16 Bs[128 * 32];
  const int tid = threadIdx.x;
  const int w = tid >> 6, lane = tid & 63;
  const int wr = w >> 1, wc = w & 1;          // 2x2 waves over 128x128
  const int lr = lane & 15, kq = lane >> 4;
  const int bm = blockIdx.x * 128, bn = blockIdx.y * 128;
  f32x4 acc[4][4] = {};
  for (int k0 = 0; k0 < Kd; k0 += 32) {
    stage_tile(A + (size_t)bm * Kd + k0, Kd, As, w, lane);
    stage_tile(B + (size_t)bn * Kd + k0, Kd, Bs, w, lane);
    __syncthreads();
    f16x8 af[4], bf[4];
#pragma unroll
    for (int mi = 0; mi < 4; ++mi)
      af[mi] = *(const f16x8*)&As[(wr * 64 + mi * 16 + lr) * 32 + kq * 8];
#pragma unroll
    for (int ni = 0; ni < 4; ++ni)
      bf[ni] = *(const f16x8*)&Bs[(wc * 64 + ni * 16 + lr) * 32 + kq * 8];
#pragma unroll
    for (int mi = 0; mi < 4; ++mi)
#pragma unroll
      for (int ni = 0; ni < 4; ++ni)
        acc[mi][ni] = __builtin_amdgcn_mfma_f32_16x16x32_f16(af[mi], bf[ni], acc[mi][ni], 0, 0, 0);
    __syncthreads();
  }
  // C/D layout: col = lane&15, row = (lane>>4)*4 + reg  [m89-verified]
#pragma unroll
  for (int mi = 0; mi < 4; ++mi) {
#pragma unroll
    for (int j = 0; j < 4; ++j) {
      const int row = bm + wr * 64 + mi * 16 + kq * 4 + j;
      float s = 1.0f;
      if (!F16OUT) s = rowscale[row];
#pragma unroll
      for (int ni = 0; ni < 4; ++ni) {
        const int col = bn + wc * 64 + ni * 16 + lr;
        if (F16OUT) C16[(size_t)row * N + col] = (_Float16)acc[mi][ni][j];
        else        C32[(size_t)row * N + col] = acc[mi][ni][j] * s;
      }
    }
  }
}

// Per (b, j-tile 128, i-chunk): MFMA S-tile = Qt * Kt^T (never materialized),
// online per-column (max, sumexp) over i, diagonal score capture.
__global__ __launch_bounds__(256)
void col_stats_mfma(const _Float16* __restrict__ qt, const _Float16* __restrict__ kt,
                    float* __restrict__ mpart, float* __restrict__ lpart,
                    float* __restrict__ sdiag, int S, int Fd, int chunk) {
  __shared__ __align__(16) _Float16 As[128 * 32];
  __shared__ __align__(16) _Float16 Bs[128 * 32];
  __shared__ float redM[8][128];
  __shared__ float redL[8][128];
  const int b = blockIdx.z, jb = blockIdx.x, ic = blockIdx.y;
  const int j0 = jb * 128;
  const _Float16* Q = qt + (size_t)b * S * Fd;
  const _Float16* K = kt + (size_t)b * S * Fd;
  const int tid = threadIdx.x;
  const int w = tid >> 6, lane = tid & 63;
  const int wr = w >> 1, wc = w & 1;
  const int lr = lane & 15, kq = lane >> 4;
  float m[4], l[4];
#pragma unroll
  for (int ni = 0; ni < 4; ++ni) { m[ni] = -3.0e38f; l[ni] = 0.0f; }

  for (int ii = 0; ii < chunk; ii += 128) {
    const int i0 = ic * chunk + ii;
    f32x4 acc[4][4] = {};
    for (int k0 = 0; k0 < Fd; k0 += 32) {
      stage_tile(Q + (size_t)i0 * Fd + k0, Fd, As, w, lane);
      stage_tile(K + (size_t)j0 * Fd + k0, Fd, Bs, w, lane);
      __syncthreads();
      f16x8 af[4], bf[4];
#pragma unroll
      for (int mi = 0; mi < 4; ++mi)
        af[mi] = *(const f16x8*)&As[(wr * 64 + mi * 16 + lr) * 32 + kq * 8];
#pragma unroll
      for (int ni = 0; ni < 4; ++ni)
        bf[ni] = *(const f16x8*)&Bs[(wc * 64 + ni * 16 + lr) * 32 + kq * 8];
#pragma unroll
      for (int mi = 0; mi < 4; ++mi)
#pragma unroll
        for (int ni = 0; ni < 4; ++ni)
          acc[mi][ni] = __builtin_amdgcn_mfma_f32_16x16x32_f16(af[mi], bf[ni], acc[mi][ni], 0, 0, 0);
      __syncthreads();
    }
    // Diagonal capture: rows of this i-tile == cols of the j-tile.
    if (i0 == j0 && wr == wc && (lr >> 2) == kq) {
      const int j = lr & 3;
#pragma unroll
      for (int mi = 0; mi < 4; ++mi)
        sdiag[(size_t)b * S + j0 + wc * 64 + mi * 16 + lr] = acc[mi][mi][j] * SCALE;
    }
    // Online (m,l) update: per lane, 4 columns (ni), 16 i-values each.
#pragma unroll
    for (int ni = 0; ni < 4; ++ni) {
      float tm = -3.0e38f;
#pragma unroll
      for (int mi = 0; mi < 4; ++mi)
#pragma unroll
        for (int j = 0; j < 4; ++j) tm = fmaxf(tm, acc[mi][ni][j]);
      tm *= SCALE;  // scale>0: max commutes with scaling
      const float mn = fmaxf(m[ni], tm);
      float add = 0.0f;
#pragma unroll
      for (int mi = 0; mi < 4; ++mi)
#pragma unroll
        for (int j = 0; j < 4; ++j) add += __expf(acc[mi][ni][j] * SCALE - mn);
      l[ni] = l[ni] * __expf(m[ni] - mn) + add;
      m[ni] = mn;
    }
  }
  // Cross-lane reduce: 8 partials per column (wr x kq), via LDS.
  __syncthreads();
  const int p = wr * 4 + kq;
#pragma unroll
  for (int ni = 0; ni < 4; ++ni) {
    const int col = wc * 64 + ni * 16 + lr;
    redM[p][col] = m[ni];
    redL[p][col] = l[ni];
  }
  __syncthreads();
  if (tid < 128) {
    float M = -3.0e38f;
#pragma unroll
    for (int q = 0; q < 8; ++q) M = fmaxf(M, redM[q][tid]);
    float L = 0.0f;
#pragma unroll
    for (int q = 0; q < 8; ++q) L += redL[q][tid] * __expf(redM[q][tid] - M);
    const size_t idx = ((size_t)ic * gridDim.z + b) * S + j0 + tid;
    mpart[idx] = M;
    lpart[idx] = L;
  }
}

__global__ __launch_bounds__(256)
void combine_diag_kernel(const float* __restrict__ mpart, const float* __restrict__ lpart,
                         const float* __restrict__ sdiag, float* __restrict__ diag, int BS) {
  const int idx = blockIdx.x * 256 + threadIdx.x;
  if (idx >= BS) return;
  float M = -3.0e38f;
#pragma unroll
  for (int c = 0; c < COLIC; ++c) M = fmaxf(M, mpart[(size_t)c * BS + idx]);
  float L = 0.0f;
#pragma unroll
  for (int c = 0; c < COLIC; ++c)
    L += lpart[(size_t)c * BS + idx] * __expf(mpart[(size_t)c * BS + idx] - M);
  diag[idx] = __expf(sdiag[idx] - M) / L;
}

extern "C" void kernel_launch(void* const* d_in, const int* in_sizes, int n_in,
                              void* d_out, int out_size, void* d_ws, size_t ws_size,
                              hipStream_t stream) {
  const float* query = (const float*)d_in[0];
  const float* key   = (const float*)d_in[1];
  const float* value = (const float*)d_in[2];
  const float* Wq    = (const float*)d_in[3];
  const float* Wk    = (const float*)d_in[4];
  const float* Wv    = (const float*)d_in[5];

  const int F = 1024;
  const int BS = in_sizes[0] / F;   // 16384
  const int B = 8;
  const int S = BS / B;             // 2048

  // ws: q16[BS*F] kv16[BS*F] wq16/wk16/wv16[F*F] mpart/lpart[COLIC*BS] sdiag/diag[BS]  ~74 MB
  _Float16* q16  = (_Float16*)d_ws;
  _Float16* kv16 = q16 + (size_t)BS * F;
  _Float16* wq16 = kv16 + (size_t)BS * F;
  _Float16* wk16 = wq16 + (size_t)F * F;
  _Float16* wv16 = wk16 + (size_t)F * F;
  float* mpart = (float*)(wv16 + (size_t)F * F);
  float* lpart = mpart + (size_t)COLIC * BS;
  float* sdiag = lpart + (size_t)COLIC * BS;
  float* diag  = sdiag + BS;

  // qt16/kt16 parked in d_out (exactly BS*F*4 bytes); dead before final GEMM writes it.
  _Float16* qt16 = (_Float16*)d_out;
  _Float16* kt16 = qt16 + (size_t)BS * F;

  const dim3 blk(256);
  const int n8x = BS * F / 8, n8w = F * F / 8;

  conv_f32_f16<<<dim3(2048), blk, 0, stream>>>(query, q16, n8x, 1.0f);
  conv_f32_f16<<<dim3(512),  blk, 0, stream>>>(Wq, wq16, n8w, 1.0f);
  conv_f32_f16<<<dim3(2048), blk, 0, stream>>>(key, kv16, n8x, 1.0f);
  conv_f32_f16<<<dim3(512),  blk, 0, stream>>>(Wk, wk16, n8w, 1.0f);
  conv_f32_f16<<<dim3(512),  blk, 0, stream>>>(Wv, wv16, n8w, 1.0f);

  const dim3 ggrid(BS / 128, F / 128);  // 128 x 8
  gemm_mfma<1><<<ggrid, blk, 0, stream>>>(q16, wq16, qt16, (float*)nullptr,
                                          (const float*)nullptr, BS, F, F);
  gemm_mfma<1><<<ggrid, blk, 0, stream>>>(kv16, wk16, kt16, (float*)nullptr,
                                          (const float*)nullptr, BS, F, F);

  // value -> fp16, reusing q16's buffer (q16 is dead after the qt GEMM)
  conv_f32_f16<<<dim3(2048), blk, 0, stream>>>(value, q16, n8x, 1.0f);

  const dim3 sgrid(S / 128, COLIC, B);  // 16 x 4 x 8 = 512 blocks
  col_stats_mfma<<<sgrid, blk, 0, stream>>>(qt16, kt16, mpart, lpart, sdiag,
                                            S, F, S / COLIC);

  combine_diag_kernel<<<dim3((BS + 255) / 256), blk, 0, stream>>>(mpart, lpart, sdiag, diag, BS);

  gemm_mfma<0><<<ggrid, blk, 0, stream>>>(q16, wv16, (_Float16*)nullptr, (float*)d_out,
                                          diag, BS, F, F);
}

// Round 4
// 329.436 us; speedup vs baseline: 7.3837x; 1.0245x over previous
//
#include <hip/hip_runtime.h>

// B=8, S=2048, F=1024 fp32 in/out.
// out[b,s,:] = diag[b,s] * (value[b,s,:] @ Wv^T)
// diag[b,j] = exp(s_jj - M_j) / sum_i exp(s_ij - M_j),  s_ij = scale * <q_t_i, k_t_j>
// All dense stages in fp16 MFMA (16x16x32, fp32 accum), m97-style 128x128 tiles.

typedef _Float16 f16x8 __attribute__((ext_vector_type(8)));
typedef float    f32x4 __attribute__((ext_vector_type(4)));

#define COLIC 8          // i-chunks for col_stats grid (1024 blocks = 4/CU)
#define SCALE 0.03125f   // 1/sqrt(1024), exact power of two

typedef __attribute__((address_space(1))) const unsigned int g_u32_t;
typedef __attribute__((address_space(3))) unsigned int l_u32_t;

__device__ __forceinline__ void gload16(const _Float16* g, _Float16* l) {
  // async global->LDS, 16 B per lane; LDS dest = wave-uniform base + lane*16
  __builtin_amdgcn_global_load_lds((g_u32_t*)g, (l_u32_t*)l, 16, 0, 0);
}

// Stage a 128x32 fp16 tile (global rows stride ldk) into LDS row-major [128][32].
__device__ __forceinline__ void stage_tile(const _Float16* gbase, int ldk,
                                           _Float16* lds, int w, int lane) {
#pragma unroll
  for (int c = 0; c < 2; ++c) {
    const int blk = c * 4 + w;                  // 0..7, wave-uniform
    const int r = (blk << 4) + (lane >> 2);     // row 0..127
    const _Float16* g = gbase + (size_t)r * ldk + ((lane & 3) << 3);
    gload16(g, lds + blk * 512);                // 512 fp16 = 1024 B per wave-call
  }
}

// Batched fp32 -> fp16 conversion: grid.y selects (src,dst) pair.
struct Conv3Args {
  const float* src[3];
  _Float16* dst[3];
};
__global__ __launch_bounds__(256)
void conv3_f32_f16(Conv3Args a, int n8) {
  const float* __restrict__ src = a.src[blockIdx.y];
  _Float16* __restrict__ dst = a.dst[blockIdx.y];
  for (int i = blockIdx.x * 256 + threadIdx.x; i < n8; i += gridDim.x * 256) {
    const float4 x = ((const float4*)src)[2 * i];
    const float4 y = ((const float4*)src)[2 * i + 1];
    f16x8 o;
    o[0] = (_Float16)x.x; o[1] = (_Float16)x.y;
    o[2] = (_Float16)x.z; o[3] = (_Float16)x.w;
    o[4] = (_Float16)y.x; o[5] = (_Float16)y.y;
    o[6] = (_Float16)y.z; o[7] = (_Float16)y.w;
    ((f16x8*)dst)[i] = o;
  }
}

// C[m][n] = sum_k A[m][k] * B[n][k];  A: MxK, B: NxK, both fp16 row-major.
// F16OUT=1: write fp16 C16.
// F16OUT=0: write fp32 C32 scaled by diag[m], diag computed inline from
//           (mpart, lpart, sdiag) in the prologue (fused combine).
template <int F16OUT>
__global__ __launch_bounds__(256)
void gemm_mfma(const _Float16* __restrict__ A, const _Float16* __restrict__ B,
               _Float16* __restrict__ C16, float* __restrict__ C32,
               const float* __restrict__ mpart, const float* __restrict__ lpart,
               const float* __restrict__ sdiag, int BSz,
               int M, int N, int Kd) {
  __shared__ __align__(16) _Float16 As[128 * 32];
  __shared__ __align__(16) _Float16 Bs[128 * 32];
  __shared__ float diagS[128];
  const int tid = threadIdx.x;
  const int w = tid >> 6, lane = tid & 63;
  const int wr = w >> 1, wc = w & 1;          // 2x2 waves over 128x128
  const int lr = lane & 15, kq = lane >> 4;
  const int bm = blockIdx.x * 128, bn = blockIdx.y * 128;

  if (!F16OUT && tid < 128) {
    // Fused combine: diag for this block's 128 rows.
    const int row = bm + tid;
    float Mx = -3.0e38f;
#pragma unroll
    for (int c = 0; c < COLIC; ++c) Mx = fmaxf(Mx, mpart[(size_t)c * BSz + row]);
    float L = 0.0f;
#pragma unroll
    for (int c = 0; c < COLIC; ++c)
      L += lpart[(size_t)c * BSz + row] * __expf(mpart[(size_t)c * BSz + row] - Mx);
    diagS[tid] = __expf(sdiag[row] - Mx) / L;
  }

  f32x4 acc[4][4] = {};
  for (int k0 = 0; k0 < Kd; k0 += 32) {
    stage_tile(A + (size_t)bm * Kd + k0, Kd, As, w, lane);
    stage_tile(B + (size_t)bn * Kd + k0, Kd, Bs, w, lane);
    __syncthreads();
    f16x8 af[4], bf[4];
#pragma unroll
    for (int mi = 0; mi < 4; ++mi)
      af[mi] = *(const f16x8*)&As[(wr * 64 + mi * 16 + lr) * 32 + kq * 8];
#pragma unroll
    for (int ni = 0; ni < 4; ++ni)
      bf[ni] = *(const f16x8*)&Bs[(wc * 64 + ni * 16 + lr) * 32 + kq * 8];
#pragma unroll
    for (int mi = 0; mi < 4; ++mi)
#pragma unroll
      for (int ni = 0; ni < 4; ++ni)
        acc[mi][ni] = __builtin_amdgcn_mfma_f32_16x16x32_f16(af[mi], bf[ni], acc[mi][ni], 0, 0, 0);
    __syncthreads();  // also makes diagS visible by epilogue
  }
  // C/D layout: col = lane&15, row = (lane>>4)*4 + reg  [m89-verified]
#pragma unroll
  for (int mi = 0; mi < 4; ++mi) {
#pragma unroll
    for (int j = 0; j < 4; ++j) {
      const int rloc = wr * 64 + mi * 16 + kq * 4 + j;
      const int row = bm + rloc;
      float s = 1.0f;
      if (!F16OUT) s = diagS[rloc];
#pragma unroll
      for (int ni = 0; ni < 4; ++ni) {
        const int col = bn + wc * 64 + ni * 16 + lr;
        if (F16OUT) C16[(size_t)row * N + col] = (_Float16)acc[mi][ni][j];
        else        C32[(size_t)row * N + col] = acc[mi][ni][j] * s;
      }
    }
  }
}

// Per (b, j-tile 128, i-chunk): MFMA S-tile = Qt * Kt^T (never materialized),
// online per-column (max, sumexp) over i, diagonal score capture.
__global__ __launch_bounds__(256)
void col_stats_mfma(const _Float16* __restrict__ qt, const _Float16* __restrict__ kt,
                    float* __restrict__ mpart, float* __restrict__ lpart,
                    float* __restrict__ sdiag, int S, int Fd, int chunk) {
  __shared__ __align__(16) _Float16 As[128 * 32];
  __shared__ __align__(16) _Float16 Bs[128 * 32];
  __shared__ float redM[8][128];
  __shared__ float redL[8][128];
  const int b = blockIdx.z, jb = blockIdx.x, ic = blockIdx.y;
  const int j0 = jb * 128;
  const _Float16* Q = qt + (size_t)b * S * Fd;
  const _Float16* K = kt + (size_t)b * S * Fd;
  const int tid = threadIdx.x;
  const int w = tid >> 6, lane = tid & 63;
  const int wr = w >> 1, wc = w & 1;
  const int lr = lane & 15, kq = lane >> 4;
  float m[4], l[4];
#pragma unroll
  for (int ni = 0; ni < 4; ++ni) { m[ni] = -3.0e38f; l[ni] = 0.0f; }

  for (int ii = 0; ii < chunk; ii += 128) {
    const int i0 = ic * chunk + ii;
    f32x4 acc[4][4] = {};
    for (int k0 = 0; k0 < Fd; k0 += 32) {
      stage_tile(Q + (size_t)i0 * Fd + k0, Fd, As, w, lane);
      stage_tile(K + (size_t)j0 * Fd + k0, Fd, Bs, w, lane);
      __syncthreads();
      f16x8 af[4], bf[4];
#pragma unroll
      for (int mi = 0; mi < 4; ++mi)
        af[mi] = *(const f16x8*)&As[(wr * 64 + mi * 16 + lr) * 32 + kq * 8];
#pragma unroll
      for (int ni = 0; ni < 4; ++ni)
        bf[ni] = *(const f16x8*)&Bs[(wc * 64 + ni * 16 + lr) * 32 + kq * 8];
#pragma unroll
      for (int mi = 0; mi < 4; ++mi)
#pragma unroll
        for (int ni = 0; ni < 4; ++ni)
          acc[mi][ni] = __builtin_amdgcn_mfma_f32_16x16x32_f16(af[mi], bf[ni], acc[mi][ni], 0, 0, 0);
      __syncthreads();
    }
    // Diagonal capture: rows of this i-tile == cols of the j-tile.
    if (i0 == j0 && wr == wc && (lr >> 2) == kq) {
      const int j = lr & 3;
#pragma unroll
      for (int mi = 0; mi < 4; ++mi)
        sdiag[(size_t)b * S + j0 + wc * 64 + mi * 16 + lr] = acc[mi][mi][j] * SCALE;
    }
    // Online (m,l) update: per lane, 4 columns (ni), 16 i-values each.
#pragma unroll
    for (int ni = 0; ni < 4; ++ni) {
      float tm = -3.0e38f;
#pragma unroll
      for (int mi = 0; mi < 4; ++mi)
#pragma unroll
        for (int j = 0; j < 4; ++j) tm = fmaxf(tm, acc[mi][ni][j]);
      tm *= SCALE;  // scale>0: max commutes with scaling
      const float mn = fmaxf(m[ni], tm);
      float add = 0.0f;
#pragma unroll
      for (int mi = 0; mi < 4; ++mi)
#pragma unroll
        for (int j = 0; j < 4; ++j) add += __expf(acc[mi][ni][j] * SCALE - mn);
      l[ni] = l[ni] * __expf(m[ni] - mn) + add;
      m[ni] = mn;
    }
  }
  // Cross-lane reduce: 8 partials per column (wr x kq), via LDS.
  __syncthreads();
  const int p = wr * 4 + kq;
#pragma unroll
  for (int ni = 0; ni < 4; ++ni) {
    const int col = wc * 64 + ni * 16 + lr;
    redM[p][col] = m[ni];
    redL[p][col] = l[ni];
  }
  __syncthreads();
  if (tid < 128) {
    float M = -3.0e38f;
#pragma unroll
    for (int q = 0; q < 8; ++q) M = fmaxf(M, redM[q][tid]);
    float L = 0.0f;
#pragma unroll
    for (int q = 0; q < 8; ++q) L += redL[q][tid] * __expf(redM[q][tid] - M);
    const size_t idx = ((size_t)ic * gridDim.z + b) * S + j0 + tid;
    mpart[idx] = M;
    lpart[idx] = L;
  }
}

extern "C" void kernel_launch(void* const* d_in, const int* in_sizes, int n_in,
                              void* d_out, int out_size, void* d_ws, size_t ws_size,
                              hipStream_t stream) {
  const float* query = (const float*)d_in[0];
  const float* key   = (const float*)d_in[1];
  const float* value = (const float*)d_in[2];
  const float* Wq    = (const float*)d_in[3];
  const float* Wk    = (const float*)d_in[4];
  const float* Wv    = (const float*)d_in[5];

  const int F = 1024;
  const int BS = in_sizes[0] / F;   // 16384
  const int B = 8;
  const int S = BS / B;             // 2048

  // ws: q16,k16,v16 [BS*F each] wq16,wk16,wv16 [F*F each]
  //     mpart,lpart [COLIC*BS] sdiag [BS]   ~108 MB total
  _Float16* q16  = (_Float16*)d_ws;
  _Float16* k16  = q16 + (size_t)BS * F;
  _Float16* v16  = k16 + (size_t)BS * F;
  _Float16* wq16 = v16 + (size_t)BS * F;
  _Float16* wk16 = wq16 + (size_t)F * F;
  _Float16* wv16 = wk16 + (size_t)F * F;
  float* mpart = (float*)(wv16 + (size_t)F * F);
  float* lpart = mpart + (size_t)COLIC * BS;
  float* sdiag = lpart + (size_t)COLIC * BS;

  // qt16/kt16 parked in d_out (exactly BS*F*4 bytes); dead before final GEMM writes it.
  _Float16* qt16 = (_Float16*)d_out;
  _Float16* kt16 = qt16 + (size_t)BS * F;

  const dim3 blk(256);
  const int n8x = BS * F / 8, n8w = F * F / 8;

  Conv3Args ax; ax.src[0] = query; ax.src[1] = key; ax.src[2] = value;
  ax.dst[0] = q16; ax.dst[1] = k16; ax.dst[2] = v16;
  conv3_f32_f16<<<dim3(2048, 3), blk, 0, stream>>>(ax, n8x);

  Conv3Args aw; aw.src[0] = Wq; aw.src[1] = Wk; aw.src[2] = Wv;
  aw.dst[0] = wq16; aw.dst[1] = wk16; aw.dst[2] = wv16;
  conv3_f32_f16<<<dim3(512, 3), blk, 0, stream>>>(aw, n8w);

  const dim3 ggrid(BS / 128, F / 128);  // 128 x 8 = 1024 blocks
  gemm_mfma<1><<<ggrid, blk, 0, stream>>>(q16, wq16, qt16, (float*)nullptr,
                                          (const float*)nullptr, (const float*)nullptr,
                                          (const float*)nullptr, BS, BS, F, F);
  gemm_mfma<1><<<ggrid, blk, 0, stream>>>(k16, wk16, kt16, (float*)nullptr,
                                          (const float*)nullptr, (const float*)nullptr,
                                          (const float*)nullptr, BS, BS, F, F);

  const dim3 sgrid(S / 128, COLIC, B);  // 16 x 8 x 8 = 1024 blocks
  col_stats_mfma<<<sgrid, blk, 0, stream>>>(qt16, kt16, mpart, lpart, sdiag,
                                            S, F, S / COLIC);

  gemm_mfma<0><<<ggrid, blk, 0, stream>>>(v16, wv16, (_Float16*)nullptr, (float*)d_out,
                                          mpart, lpart, sdiag, BS, BS, F, F);
}